// Round 3
// baseline (347.608 us; speedup 1.0000x reference)
//
#include <hip/hip_runtime.h>

// OTTT single step:
//   u_pre  = sig_tau * u + x @ W + b
//   s      = (u_pre >= 1.0)
//   u_new  = u_pre - s
//   a_hat' = sig_tau * a_hat + x
// Outputs concatenated: [s (8192) | u_new (8192) | a_hat_new (8192)], f32.
//
// HBM-bound GEMV: W = 256 MiB f32 read dominates (~43 us floor at ~6.7 TB/s
// achieved BW). R4: FULLY FUSED single kernel — no split-K partials, no
// second launch, no workspace usage at all.
//
// Structure: grid = 256 blocks x 512 threads (1 block/CU, 8 waves/CU).
//  - Block b owns 8 float4-columns (cols 32b..32b+31) = 128 B per W row,
//    exactly one L2 line -> each line is consumed by exactly one block
//    (no cross-block/cross-XCD line splitting, no over-fetch).
//  - Thread t: f4col = t&7, row-group = t>>3 (64 groups x 128 rows).
//    Per thread: 128 nontemporal dwordx4 loads, unroll 8 -> 8 KB in
//    flight/wave, 64 KB/CU (>> ~20 KB needed at 6.7 TB/s).
//  - x staged once in LDS (32 KB); also reused for the a_hat epilogue.
//  - Reduction: LDS tree 64 -> 8 -> 1 in fixed ascending order
//    (deterministic, atomics-free) + LIF epilogue in the same kernel.

#define IN_DIM   8192
#define OUT_DIM  8192
#define SIG_TAU  0.8807970779778823f   // sigmoid(2.0)
#define V_TH     1.0f

#define BLK_THREADS  512
#define FC_PER_BLK   8                       // 8 f4-cols = 128 B/row/block
#define ROW_GROUPS   (BLK_THREADS / FC_PER_BLK)      // 64
#define ROWS_PER_THR (IN_DIM / ROW_GROUPS)           // 128
#define NBLOCKS      (OUT_DIM / 4 / FC_PER_BLK)      // 256

typedef float f4 __attribute__((ext_vector_type(4)));

__global__ __launch_bounds__(BLK_THREADS) void ottt_fused(
    const float* __restrict__ W,
    const float* __restrict__ b,
    const float* __restrict__ u,
    const float* __restrict__ a_hat,
    const float* __restrict__ x,
    float* __restrict__ out)
{
    __shared__ float xs[IN_DIM];                       // 32 KB
    __shared__ f4 red[ROW_GROUPS][FC_PER_BLK];         // 8 KB
    __shared__ f4 red2[8][FC_PER_BLK];                 // 2 KB

    // Stage all of x into LDS (coalesced f4 loads).
    f4* xs4 = (f4*)xs;
    #pragma unroll
    for (int i = 0; i < IN_DIM / 4 / BLK_THREADS; ++i)   // 4 iters
        xs4[threadIdx.x + i * BLK_THREADS] =
            ((const f4*)x)[threadIdx.x + i * BLK_THREADS];
    __syncthreads();

    const int fc   = threadIdx.x & (FC_PER_BLK - 1);   // f4-col within block
    const int rg   = threadIdx.x >> 3;                 // row group 0..63
    const int c4   = blockIdx.x * FC_PER_BLK + fc;     // global f4-col
    const int row0 = rg * ROWS_PER_THR;

    // Wave lanes 0..7 read 8 consecutive f4s of one row = 128 B contiguous.
    const f4* Wp = (const f4*)W + (size_t)row0 * (OUT_DIM / 4) + c4;
    f4 acc = {0.f, 0.f, 0.f, 0.f};

    #pragma unroll 8
    for (int r = 0; r < ROWS_PER_THR; ++r) {
        // Nontemporal: W streamed exactly once; keep L2 for x/out/vectors.
        const f4 w = __builtin_nontemporal_load(&Wp[(size_t)r * (OUT_DIM / 4)]);
        const float xv = xs[row0 + r];
        acc.x = fmaf(xv, w.x, acc.x);
        acc.y = fmaf(xv, w.y, acc.y);
        acc.z = fmaf(xv, w.z, acc.z);
        acc.w = fmaf(xv, w.w, acc.w);
    }

    red[rg][fc] = acc;
    __syncthreads();

    // Tree stage 1: 64 row-groups -> 8 (fixed ascending order, deterministic).
    if (threadIdx.x < 64) {
        const int f = threadIdx.x & 7;
        const int g = threadIdx.x >> 3;
        f4 s = red[g * 8][f];
        #pragma unroll
        for (int j = 1; j < 8; ++j) {
            const f4 r = red[g * 8 + j][f];
            s.x += r.x; s.y += r.y; s.z += r.z; s.w += r.w;
        }
        red2[g][f] = s;
    }
    __syncthreads();

    // Tree stage 2 + LIF epilogue + a_hat, one f4-col per thread.
    if (threadIdx.x < FC_PER_BLK) {
        const int c4g = blockIdx.x * FC_PER_BLK + threadIdx.x;

        f4 sum = red2[0][threadIdx.x];
        #pragma unroll
        for (int g = 1; g < 8; ++g) {
            const f4 r = red2[g][threadIdx.x];
            sum.x += r.x; sum.y += r.y; sum.z += r.z; sum.w += r.w;
        }

        const f4 b4  = ((const f4*)b)[c4g];
        const f4 u4  = ((const f4*)u)[c4g];
        const f4 ah4 = ((const f4*)a_hat)[c4g];
        const f4 x4  = xs4[c4g];   // IN_DIM == OUT_DIM: same index range

        f4 s4, un4, an4;
        {
            const float up = fmaf(SIG_TAU, u4.x, sum.x + b4.x);
            s4.x = (up >= V_TH) ? 1.0f : 0.0f; un4.x = up - s4.x * V_TH;
            an4.x = fmaf(SIG_TAU, ah4.x, x4.x);
        }
        {
            const float up = fmaf(SIG_TAU, u4.y, sum.y + b4.y);
            s4.y = (up >= V_TH) ? 1.0f : 0.0f; un4.y = up - s4.y * V_TH;
            an4.y = fmaf(SIG_TAU, ah4.y, x4.y);
        }
        {
            const float up = fmaf(SIG_TAU, u4.z, sum.z + b4.z);
            s4.z = (up >= V_TH) ? 1.0f : 0.0f; un4.z = up - s4.z * V_TH;
            an4.z = fmaf(SIG_TAU, ah4.z, x4.z);
        }
        {
            const float up = fmaf(SIG_TAU, u4.w, sum.w + b4.w);
            s4.w = (up >= V_TH) ? 1.0f : 0.0f; un4.w = up - s4.w * V_TH;
            an4.w = fmaf(SIG_TAU, ah4.w, x4.w);
        }

        f4* o = (f4*)out;
        o[c4g]                     = s4;
        o[(OUT_DIM / 4) + c4g]     = un4;
        o[2 * (OUT_DIM / 4) + c4g] = an4;
    }
}

extern "C" void kernel_launch(void* const* d_in, const int* in_sizes, int n_in,
                              void* d_out, int out_size, void* d_ws, size_t ws_size,
                              hipStream_t stream)
{
    const float* W     = (const float*)d_in[0];
    const float* b     = (const float*)d_in[1];
    const float* u     = (const float*)d_in[2];
    const float* a_hat = (const float*)d_in[3];
    const float* x     = (const float*)d_in[4];
    float* out = (float*)d_out;

    (void)d_ws; (void)ws_size;   // fused path needs no workspace

    ottt_fused<<<NBLOCKS, BLK_THREADS, 0, stream>>>(W, b, u, a_hat, x, out);
}